// Round 1
// baseline (456.251 us; speedup 1.0000x reference)
//
#include <hip/hip_runtime.h>
#include <stdint.h>

#define NN 8192
#define INC 256
#define OUTC 64
#define LOG2E 1.4426950408889634f

typedef __bf16 bf16x8 __attribute__((ext_vector_type(8)));
typedef float f32x4 __attribute__((ext_vector_type(4)));

__device__ __forceinline__ unsigned short f2bf(float x) {
    union { float f; unsigned u; } v; v.f = x;
    unsigned u = v.u;
    u += 0x7fffu + ((u >> 16) & 1u);   // RNE, inputs never NaN
    return (unsigned short)(u >> 16);
}

#if __has_builtin(__builtin_amdgcn_exp2f)
#define EXP2(x) __builtin_amdgcn_exp2f(x)
#else
#define EXP2(x) exp2f(x)
#endif

// K0: Wa1[k] = sum_c W[k][c]*a[c];  Wa2[k] = sum_c W[k][c]*a[64+c]
__global__ void gat_k0(const float* __restrict__ W, const float* __restrict__ a,
                       float* __restrict__ Wa1, float* __restrict__ Wa2) {
    int k = threadIdx.x;  // 256 threads
    float s1 = 0.f, s2 = 0.f;
    #pragma unroll 8
    for (int c = 0; c < OUTC; ++c) {
        float w = W[k * OUTC + c];
        s1 = fmaf(w, a[c], s1);
        s2 = fmaf(w, a[OUTC + c], s2);
    }
    Wa1[k] = s1; Wa2[k] = s2;
}

// K1: per 16-row block: WhT(bf16, [64][8192]) + Wh1[i] + Wh2[i]
__global__ __launch_bounds__(256) void gat_k1(
        const float* __restrict__ h, const float* __restrict__ W,
        const float* __restrict__ Wa1, const float* __restrict__ Wa2,
        unsigned short* __restrict__ WhT, float* __restrict__ Wh1,
        float* __restrict__ Wh2) {
    __shared__ float hs[16 * INC];          // 16 KB
    __shared__ unsigned short wt[OUTC][16]; // 2 KB transpose buffer
    const int r0 = blockIdx.x * 16;
    const int t  = threadIdx.x;
    // stage 16 rows of h (4096 floats), coalesced float4
    #pragma unroll
    for (int it = 0; it < 4; ++it) {
        int idx = it * 1024 + t * 4;
        float4 v = *reinterpret_cast<const float4*>(h + (size_t)r0 * INC + idx);
        hs[idx] = v.x; hs[idx + 1] = v.y; hs[idx + 2] = v.z; hs[idx + 3] = v.w;
    }
    __syncthreads();
    const int w = t >> 6, lane = t & 63;
    const int c = lane;                 // one channel per lane
    const float* hr = &hs[w * 4 * INC]; // this wave's 4 rows
    float acc0 = 0.f, acc1 = 0.f, acc2 = 0.f, acc3 = 0.f;
    #pragma unroll 8
    for (int k = 0; k < INC; ++k) {
        float wv = W[k * OUTC + c];     // coalesced, L2-hot
        acc0 = fmaf(hr[k],           wv, acc0);
        acc1 = fmaf(hr[INC + k],     wv, acc1);
        acc2 = fmaf(hr[2 * INC + k], wv, acc2);
        acc3 = fmaf(hr[3 * INC + k], wv, acc3);
    }
    // Wh1/Wh2 = h . (W@a): lane-parallel over k then butterfly reduce
    float s1r[4] = {0.f, 0.f, 0.f, 0.f}, s2r[4] = {0.f, 0.f, 0.f, 0.f};
    #pragma unroll
    for (int kk = 0; kk < 4; ++kk) {
        int k = kk * 64 + lane;
        float wa1v = Wa1[k], wa2v = Wa2[k];
        #pragma unroll
        for (int r = 0; r < 4; ++r) {
            float hv = hr[r * INC + k];
            s1r[r] = fmaf(hv, wa1v, s1r[r]);
            s2r[r] = fmaf(hv, wa2v, s2r[r]);
        }
    }
    #pragma unroll
    for (int r = 0; r < 4; ++r) {
        float s1 = s1r[r], s2 = s2r[r];
        #pragma unroll
        for (int off = 32; off; off >>= 1) {
            s1 += __shfl_xor(s1, off, 64);
            s2 += __shfl_xor(s2, off, 64);
        }
        if (lane == 0) { Wh1[r0 + w * 4 + r] = s1; Wh2[r0 + w * 4 + r] = s2; }
    }
    // transpose Wh tile to bf16 via LDS, then coalesced ushort4 stores
    wt[c][w * 4 + 0] = f2bf(acc0);
    wt[c][w * 4 + 1] = f2bf(acc1);
    wt[c][w * 4 + 2] = f2bf(acc2);
    wt[c][w * 4 + 3] = f2bf(acc3);
    __syncthreads();
    int cc = t >> 2, seg = t & 3;
    ushort4 v;
    v.x = wt[cc][seg * 4 + 0]; v.y = wt[cc][seg * 4 + 1];
    v.z = wt[cc][seg * 4 + 2]; v.w = wt[cc][seg * 4 + 3];
    *reinterpret_cast<ushort4*>(WhT + (size_t)cc * NN + r0 + seg * 4) = v;
}

// K2: M = max(Wh2)
__global__ void gat_k2(const float* __restrict__ Wh2, float* __restrict__ M) {
    __shared__ float red[4];
    int t = threadIdx.x;  // 256
    float m = -1e30f;
    for (int i = t; i < NN; i += 256) m = fmaxf(m, Wh2[i]);
    #pragma unroll
    for (int off = 32; off; off >>= 1) m = fmaxf(m, __shfl_xor(m, off, 64));
    if ((t & 63) == 0) red[t >> 6] = m;
    __syncthreads();
    if (t == 0) *M = fmaxf(fmaxf(red[0], red[1]), fmaxf(red[2], red[3]));
}

// K3: main fused attention. 512 blocks x 512 threads; 16 rows/block; 8 waves split j.
__global__ __launch_bounds__(512) void gat_k3(
        const int* __restrict__ adj, const unsigned short* __restrict__ WhT,
        const float* __restrict__ Wh1, const float* __restrict__ Wh2,
        const float* __restrict__ Mp, float* __restrict__ out) {
    __shared__ float accs[8][16 * OUTC]; // 32 KB
    __shared__ float ls[8][16];
    const int r0 = blockIdx.x * 16;
    const int t = threadIdx.x;
    const int w = t >> 6, lane = t & 63;
    const int m = lane & 15, q = lane >> 4;
    const int row = r0 + m;
    const float wh1 = Wh1[row];
    const float Mv = *Mp;
    const float sM = wh1 + Mv;
    const float mhat = fmaxf(sM, 0.5f * sM);       // leaky(wh1 + max Wh2) >= row max
    const float mh2 = mhat * LOG2E;
    const int* __restrict__ arow = adj + (size_t)row * NN;
    f32x4 acc[4] = {{0,0,0,0},{0,0,0,0},{0,0,0,0},{0,0,0,0}};
    float lpart = 0.f;

    for (int jt = w; jt < NN / 32; jt += 8) {
        const int j0 = jt * 32 + q * 8;
        int4 ai0 = *reinterpret_cast<const int4*>(arow + j0);
        int4 ai1 = *reinterpret_cast<const int4*>(arow + j0 + 4);
        float4 w20 = *reinterpret_cast<const float4*>(Wh2 + j0);
        float4 w21 = *reinterpret_cast<const float4*>(Wh2 + j0 + 4);
        float p[8];
        {
            float sv[8] = {w20.x, w20.y, w20.z, w20.w, w21.x, w21.y, w21.z, w21.w};
            int   av[8] = {ai0.x, ai0.y, ai0.z, ai0.w, ai1.x, ai1.y, ai1.z, ai1.w};
            #pragma unroll
            for (int e = 0; e < 8; ++e) {
                float s  = wh1 + sv[e];
                float lk = fmaxf(s, 0.5f * s);            // leakyrelu(0.5)
                float ar = fmaf(lk, LOG2E, -mh2);         // (lk - mhat)*log2e
                float pe = EXP2(ar);
                p[e] = (av[e] > 0) ? pe : 0.f;
            }
        }
        lpart += ((p[0] + p[1]) + (p[2] + p[3])) + ((p[4] + p[5]) + (p[6] + p[7]));
        bf16x8 af;
        #pragma unroll
        for (int e = 0; e < 8; ++e) af[e] = (__bf16)p[e];
        #pragma unroll
        for (int ct = 0; ct < 4; ++ct) {
            const int cidx = ct * 16 + m;   // B-frag: n = lane&15, k = q*8+t
            bf16x8 bfv = *reinterpret_cast<const bf16x8*>(WhT + (size_t)cidx * NN + j0);
            acc[ct] = __builtin_amdgcn_mfma_f32_16x16x32_bf16(af, bfv, acc[ct], 0, 0, 0);
        }
    }
    // dump accumulators: C/D layout col=lane&15, row=q*4+reg
    #pragma unroll
    for (int ct = 0; ct < 4; ++ct)
        #pragma unroll
        for (int r = 0; r < 4; ++r)
            accs[w][(q * 4 + r) * OUTC + ct * 16 + m] = acc[ct][r];
    // row-sum l: lanes {m, m+16, m+32, m+48} hold partials of row m
    float l = lpart;
    l += __shfl_xor(l, 16, 64);
    l += __shfl_xor(l, 32, 64);
    if (lane < 16) ls[w][lane] = l;
    __syncthreads();
    for (int e = t; e < 16 * OUTC; e += 512) {
        int rr = e >> 6, cc = e & 63;
        float s = 0.f;
        #pragma unroll
        for (int ww = 0; ww < 8; ++ww) s += accs[ww][e];
        float lsum = 0.f;
        #pragma unroll
        for (int ww = 0; ww < 8; ++ww) lsum += ls[ww][rr];
        float o = s / lsum;
        out[(size_t)(r0 + rr) * OUTC + cc] = o > 0.f ? o : 0.f;
    }
}

extern "C" void kernel_launch(void* const* d_in, const int* in_sizes, int n_in,
                              void* d_out, int out_size, void* d_ws, size_t ws_size,
                              hipStream_t stream) {
    const float* h   = (const float*)d_in[0];
    const int*   adj = (const int*)d_in[1];
    const float* W   = (const float*)d_in[2];
    const float* a   = (const float*)d_in[3];
    float* out = (float*)d_out;

    char* base = (char*)d_ws;
    float* Wa1 = (float*)(base);                 // 256 f  @ 0
    float* Wa2 = (float*)(base + 1024);          // 256 f  @ 1 KB
    float* Wh1 = (float*)(base + 2048);          // 8192 f @ 2 KB
    float* Wh2 = (float*)(base + 34816);         // 8192 f @ 34 KB
    float* Mp  = (float*)(base + 67584);         // 1 f
    unsigned short* WhT = (unsigned short*)(base + 67600); // 64*8192 bf16 = 1 MB

    gat_k0<<<1, 256, 0, stream>>>(W, a, Wa1, Wa2);
    gat_k1<<<NN / 16, 256, 0, stream>>>(h, W, Wa1, Wa2, WhT, Wh1, Wh2);
    gat_k2<<<1, 256, 0, stream>>>(Wh2, Mp);
    gat_k3<<<NN / 16, 512, 0, stream>>>(adj, WhT, Wh1, Wh2, Mp, out);
}

// Round 2
// 398.299 us; speedup vs baseline: 1.1455x; 1.1455x over previous
//
#include <hip/hip_runtime.h>
#include <stdint.h>

#define NN 8192
#define INC 256
#define OUTC 64
#define LOG2E 1.4426950408889634f

typedef __bf16 bf16x8 __attribute__((ext_vector_type(8)));
typedef float f32x4 __attribute__((ext_vector_type(4)));

__device__ __forceinline__ unsigned short f2bf(float x) {
    union { float f; unsigned u; } v; v.f = x;
    unsigned u = v.u;
    u += 0x7fffu + ((u >> 16) & 1u);   // RNE, inputs never NaN
    return (unsigned short)(u >> 16);
}

#if __has_builtin(__builtin_amdgcn_exp2f)
#define EXP2(x) __builtin_amdgcn_exp2f(x)
#else
#define EXP2(x) exp2f(x)
#endif

// K1: per 16-row block: Wh -> WhTf (MFMA-B-frag interleaved bf16) + Wh1[i] + Wh2[i]
// W staged in LDS (padded stride 65 -> conflict-free), a staged, Wa computed per block.
__global__ __launch_bounds__(256) void gat_k1(
        const float* __restrict__ h, const float* __restrict__ W,
        const float* __restrict__ a,
        unsigned short* __restrict__ WhTf, float* __restrict__ Wh1,
        float* __restrict__ Wh2) {
    __shared__ float Ws[256 * 65];          // 65 KB, padded
    __shared__ float hs[16 * INC];          // 16 KB
    __shared__ float Wa1s[256], Wa2s[256], as_[128];
    __shared__ unsigned short wt[OUTC][16]; // transpose buffer
    const int r0 = blockIdx.x * 16;
    const int t  = threadIdx.x;
    if (t < 128) as_[t] = a[t];
    // stage W: 16384 floats, coalesced float4, into padded rows
    #pragma unroll
    for (int it = 0; it < 16; ++it) {
        int idx = it * 1024 + t * 4;        // flat index into W
        float4 v = *reinterpret_cast<const float4*>(W + idx);
        int k = idx >> 6, c = idx & 63;
        float* dst = &Ws[k * 65 + c];
        dst[0] = v.x; dst[1] = v.y; dst[2] = v.z; dst[3] = v.w;
    }
    // stage 16 rows of h (4096 floats)
    #pragma unroll
    for (int it = 0; it < 4; ++it) {
        int idx = it * 1024 + t * 4;
        float4 v = *reinterpret_cast<const float4*>(h + (size_t)r0 * INC + idx);
        hs[idx] = v.x; hs[idx + 1] = v.y; hs[idx + 2] = v.z; hs[idx + 3] = v.w;
    }
    __syncthreads();
    // Wa from LDS: thread t handles k=t
    {
        float s1 = 0.f, s2 = 0.f;
        #pragma unroll 8
        for (int c = 0; c < OUTC; ++c) {
            float w = Ws[t * 65 + c];
            s1 = fmaf(w, as_[c], s1);
            s2 = fmaf(w, as_[OUTC + c], s2);
        }
        Wa1s[t] = s1; Wa2s[t] = s2;
    }
    __syncthreads();
    const int w = t >> 6, lane = t & 63;
    const int c = lane;
    const float* hr = &hs[w * 4 * INC];     // this wave's 4 rows
    float acc0 = 0.f, acc1 = 0.f, acc2 = 0.f, acc3 = 0.f;
    #pragma unroll 8
    for (int k = 0; k < INC; ++k) {
        float wv = Ws[k * 65 + c];          // conflict-free (stride-1 lanes)
        acc0 = fmaf(hr[k],           wv, acc0);
        acc1 = fmaf(hr[INC + k],     wv, acc1);
        acc2 = fmaf(hr[2 * INC + k], wv, acc2);
        acc3 = fmaf(hr[3 * INC + k], wv, acc3);
    }
    // Wh1/Wh2: lane-parallel over k then butterfly reduce
    float s1r[4] = {0.f, 0.f, 0.f, 0.f}, s2r[4] = {0.f, 0.f, 0.f, 0.f};
    #pragma unroll
    for (int kk = 0; kk < 4; ++kk) {
        int k = kk * 64 + lane;
        float wa1v = Wa1s[k], wa2v = Wa2s[k];
        #pragma unroll
        for (int r = 0; r < 4; ++r) {
            float hv = hr[r * INC + k];
            s1r[r] = fmaf(hv, wa1v, s1r[r]);
            s2r[r] = fmaf(hv, wa2v, s2r[r]);
        }
    }
    #pragma unroll
    for (int r = 0; r < 4; ++r) {
        float s1 = s1r[r], s2 = s2r[r];
        #pragma unroll
        for (int off = 32; off; off >>= 1) {
            s1 += __shfl_xor(s1, off, 64);
            s2 += __shfl_xor(s2, off, 64);
        }
        if (lane == 0) { Wh1[r0 + w * 4 + r] = s1; Wh2[r0 + w * 4 + r] = s2; }
    }
    // transpose Wh tile to bf16
    wt[c][w * 4 + 0] = f2bf(acc0);
    wt[c][w * 4 + 1] = f2bf(acc1);
    wt[c][w * 4 + 2] = f2bf(acc2);
    wt[c][w * 4 + 3] = f2bf(acc3);
    __syncthreads();
    // write WhTf in MFMA-B-frag interleaved layout:
    // frag_id = (j>>5)*4 + (c>>4); elem = frag_id*512 + (((j>>3)&3)*16 + (c&15))*8 + (j&7)
    if (t < 128) {
        int m = t & 15, ct = (t >> 4) & 3, oct = t >> 6;
        int Kb = r0 >> 5;
        int qh = (r0 >> 3) & 3;              // 0 or 2
        int lanef = (qh + oct) * 16 + m;
        int cidx = ct * 16 + m;
        ushort4 v0, v1;
        v0.x = wt[cidx][oct * 8 + 0]; v0.y = wt[cidx][oct * 8 + 1];
        v0.z = wt[cidx][oct * 8 + 2]; v0.w = wt[cidx][oct * 8 + 3];
        v1.x = wt[cidx][oct * 8 + 4]; v1.y = wt[cidx][oct * 8 + 5];
        v1.z = wt[cidx][oct * 8 + 6]; v1.w = wt[cidx][oct * 8 + 7];
        unsigned short* dst = WhTf + (((size_t)(Kb * 4 + ct)) << 9) + lanef * 8;
        *reinterpret_cast<ushort4*>(dst)     = v0;
        *reinterpret_cast<ushort4*>(dst + 4) = v1;
    }
}

// K2: M = max(Wh2)
__global__ void gat_k2(const float* __restrict__ Wh2, float* __restrict__ M) {
    __shared__ float red[16];
    int t = threadIdx.x;  // 1024
    float4 v0 = *reinterpret_cast<const float4*>(Wh2 + t * 4);
    float4 v1 = *reinterpret_cast<const float4*>(Wh2 + 4096 + t * 4);
    float m = fmaxf(fmaxf(fmaxf(v0.x, v0.y), fmaxf(v0.z, v0.w)),
                    fmaxf(fmaxf(v1.x, v1.y), fmaxf(v1.z, v1.w)));
    #pragma unroll
    for (int off = 32; off; off >>= 1) m = fmaxf(m, __shfl_xor(m, off, 64));
    if ((t & 63) == 0) red[t >> 6] = m;
    __syncthreads();
    if (t == 0) {
        float mm = red[0];
        #pragma unroll
        for (int i = 1; i < 16; ++i) mm = fmaxf(mm, red[i]);
        *M = mm;
    }
}

// K3: main fused attention. 512 blocks x 512 threads; 16 rows/block; 8 waves split j.
// 64 j per wave-iteration, explicit adj prefetch, coalesced WhTf frag loads, Wh2 in LDS.
__global__ __launch_bounds__(512, 4) void gat_k3(
        const int* __restrict__ adj, const unsigned short* __restrict__ WhTf,
        const float* __restrict__ Wh1, const float* __restrict__ Wh2,
        const float* __restrict__ Mp, float* __restrict__ out) {
    __shared__ float accs[8][16 * OUTC]; // 32 KB
    __shared__ float wh2s[NN];           // 32 KB
    __shared__ float ls[8][16];
    const int r0 = blockIdx.x * 16;
    const int t = threadIdx.x;
    const int w = t >> 6, lane = t & 63;
    const int m = lane & 15, q = lane >> 4;
    // stage Wh2
    #pragma unroll
    for (int it = 0; it < 4; ++it) {
        int idx = it * 2048 + t * 4;
        float4 v = *reinterpret_cast<const float4*>(Wh2 + idx);
        wh2s[idx] = v.x; wh2s[idx + 1] = v.y; wh2s[idx + 2] = v.z; wh2s[idx + 3] = v.w;
    }
    const int row = r0 + m;
    const float wh1 = Wh1[row];
    const float Mv = *Mp;
    const float sM = wh1 + Mv;
    const float mhat = fmaxf(sM, 0.5f * sM);       // leaky(wh1 + max Wh2) >= row max
    const float mh2 = mhat * LOG2E;
    const int* __restrict__ arow = adj + (size_t)row * NN;
    __syncthreads();
    f32x4 acc[4] = {{0,0,0,0},{0,0,0,0},{0,0,0,0},{0,0,0,0}};
    float lpart = 0.f;

    const int qo = q * 8;
    int jt = w;                    // 64-wide k-blocks: 128 total, 8 waves
    // preload first adj tile
    int4 a0 = *reinterpret_cast<const int4*>(arow + jt * 64 + qo);
    int4 a1 = *reinterpret_cast<const int4*>(arow + jt * 64 + qo + 4);
    int4 a2 = *reinterpret_cast<const int4*>(arow + jt * 64 + 32 + qo);
    int4 a3 = *reinterpret_cast<const int4*>(arow + jt * 64 + 32 + qo + 4);

    #pragma unroll 2
    for (int it = 0; it < 16; ++it, jt += 8) {
        // 1) issue WhTf fragment loads (coalesced 16 B/lane, L2-hot)
        const unsigned short* fb = WhTf + (size_t)jt * 4096 + lane * 8;
        bf16x8 bv0 = *reinterpret_cast<const bf16x8*>(fb);
        bf16x8 bv1 = *reinterpret_cast<const bf16x8*>(fb + 512);
        bf16x8 bv2 = *reinterpret_cast<const bf16x8*>(fb + 1024);
        bf16x8 bv3 = *reinterpret_cast<const bf16x8*>(fb + 1536);
        bf16x8 bv4 = *reinterpret_cast<const bf16x8*>(fb + 2048);
        bf16x8 bv5 = *reinterpret_cast<const bf16x8*>(fb + 2560);
        bf16x8 bv6 = *reinterpret_cast<const bf16x8*>(fb + 3072);
        bf16x8 bv7 = *reinterpret_cast<const bf16x8*>(fb + 3584);
        // 2) issue next adj tile (stays in flight across the MFMA waits)
        const int jn = (it < 15) ? jt + 8 : w;
        const int* __restrict__ anext = arow + jn * 64 + qo;
        int4 n0 = *reinterpret_cast<const int4*>(anext);
        int4 n1 = *reinterpret_cast<const int4*>(anext + 4);
        int4 n2 = *reinterpret_cast<const int4*>(anext + 32);
        int4 n3 = *reinterpret_cast<const int4*>(anext + 36);
        // 3) p for both 32-halves (adj in regs, Wh2 from LDS)
        const int jb = jt * 64 + qo;
        float4 s0 = *reinterpret_cast<const float4*>(&wh2s[jb]);
        float4 s1 = *reinterpret_cast<const float4*>(&wh2s[jb + 4]);
        float4 s2 = *reinterpret_cast<const float4*>(&wh2s[jb + 32]);
        float4 s3 = *reinterpret_cast<const float4*>(&wh2s[jb + 36]);
        float sv[16] = {s0.x, s0.y, s0.z, s0.w, s1.x, s1.y, s1.z, s1.w,
                        s2.x, s2.y, s2.z, s2.w, s3.x, s3.y, s3.z, s3.w};
        int   av[16] = {a0.x, a0.y, a0.z, a0.w, a1.x, a1.y, a1.z, a1.w,
                        a2.x, a2.y, a2.z, a2.w, a3.x, a3.y, a3.z, a3.w};
        float p[16];
        #pragma unroll
        for (int e = 0; e < 16; ++e) {
            float s  = wh1 + sv[e];
            float lk = fmaxf(s, 0.5f * s);            // leakyrelu(0.5)
            float ar = fmaf(lk, LOG2E, -mh2);
            float pe = EXP2(ar);
            p[e] = (av[e] > 0) ? pe : 0.f;
        }
        float lp = 0.f;
        #pragma unroll
        for (int e = 0; e < 16; ++e) lp += p[e];
        lpart += lp;
        bf16x8 af0, af1;
        #pragma unroll
        for (int e = 0; e < 8; ++e) { af0[e] = (__bf16)p[e]; af1[e] = (__bf16)p[8 + e]; }
        // 4) MFMA (waits only on WhTf frags; next-adj stays outstanding)
        acc[0] = __builtin_amdgcn_mfma_f32_16x16x32_bf16(af0, bv0, acc[0], 0, 0, 0);
        acc[1] = __builtin_amdgcn_mfma_f32_16x16x32_bf16(af0, bv1, acc[1], 0, 0, 0);
        acc[2] = __builtin_amdgcn_mfma_f32_16x16x32_bf16(af0, bv2, acc[2], 0, 0, 0);
        acc[3] = __builtin_amdgcn_mfma_f32_16x16x32_bf16(af0, bv3, acc[3], 0, 0, 0);
        acc[0] = __builtin_amdgcn_mfma_f32_16x16x32_bf16(af1, bv4, acc[0], 0, 0, 0);
        acc[1] = __builtin_amdgcn_mfma_f32_16x16x32_bf16(af1, bv5, acc[1], 0, 0, 0);
        acc[2] = __builtin_amdgcn_mfma_f32_16x16x32_bf16(af1, bv6, acc[2], 0, 0, 0);
        acc[3] = __builtin_amdgcn_mfma_f32_16x16x32_bf16(af1, bv7, acc[3], 0, 0, 0);
        a0 = n0; a1 = n1; a2 = n2; a3 = n3;
    }
    // dump accumulators: C/D layout col=lane&15, row=q*4+reg
    #pragma unroll
    for (int ct = 0; ct < 4; ++ct)
        #pragma unroll
        for (int r = 0; r < 4; ++r)
            accs[w][(q * 4 + r) * OUTC + ct * 16 + m] = acc[ct][r];
    float l = lpart;
    l += __shfl_xor(l, 16, 64);
    l += __shfl_xor(l, 32, 64);
    if (lane < 16) ls[w][lane] = l;
    __syncthreads();
    for (int e = t; e < 16 * OUTC; e += 512) {
        int rr = e >> 6, cc = e & 63;
        float s = 0.f;
        #pragma unroll
        for (int ww = 0; ww < 8; ++ww) s += accs[ww][e];
        float lsum = 0.f;
        #pragma unroll
        for (int ww = 0; ww < 8; ++ww) lsum += ls[ww][rr];
        float o = s / lsum;
        out[(size_t)(r0 + rr) * OUTC + cc] = o > 0.f ? o : 0.f;
    }
}

extern "C" void kernel_launch(void* const* d_in, const int* in_sizes, int n_in,
                              void* d_out, int out_size, void* d_ws, size_t ws_size,
                              hipStream_t stream) {
    const float* h   = (const float*)d_in[0];
    const int*   adj = (const int*)d_in[1];
    const float* W   = (const float*)d_in[2];
    const float* a   = (const float*)d_in[3];
    float* out = (float*)d_out;

    char* base = (char*)d_ws;
    float* Wh1 = (float*)(base);                 // 8192 f @ 0
    float* Wh2 = (float*)(base + 32768);         // 8192 f @ 32 KB
    float* Mp  = (float*)(base + 65536);         // 1 f
    unsigned short* WhTf = (unsigned short*)(base + 69632); // 64*8192 bf16 = 1 MB

    gat_k1<<<NN / 16, 256, 0, stream>>>(h, W, a, WhTf, Wh1, Wh2);
    gat_k2<<<1, 1024, 0, stream>>>(Wh2, Mp);
    gat_k3<<<NN / 16, 512, 0, stream>>>(adj, WhTf, Wh1, Wh2, Mp, out);
}